// Round 3
// baseline (236.954 us; speedup 1.0000x reference)
//
#include <hip/hip_runtime.h>
#include <hip/hip_bf16.h>

#define F_IN 128
#define HID  64
#define NCLS 19
#define BW   128          // nodes per bucket (dst >> 7)
#define NBMAX 512         // max buckets (N <= 65536); also sortA scan width
#define ACAP 3072         // edges per k_sortA block (12 KB lbuf; ~2 blocks/CU co-resident)
#define BKCAP 5120        // static per-bucket capacity (mean 4096, sigma 64 -> 16-sigma safe)
#define W1STR 136         // padded LDS stride (shorts) for W1^T rows
#define W2STR 72          // padded LDS stride (shorts) for W2^T rows

typedef __bf16 bf16x8 __attribute__((ext_vector_type(8)));
typedef float  f32x4  __attribute__((ext_vector_type(4)));

// -------- adaptive loads: flags[0]=1 -> floats are fp32 (else bf16)
//          flags[1]=1 -> indices are int64 (else int32)
__device__ __forceinline__ float ldf(const void* p, long i, int fp32) {
    if (fp32) return ((const float*)p)[i];
    return __bfloat162float(((const __hip_bfloat16*)p)[i]);
}
__device__ __forceinline__ int ldi(const void* p, long i, int i64) {
    if (i64) return (int)((const long long*)p)[i];
    return ((const int*)p)[i];
}
__device__ __forceinline__ unsigned short f2bf(float f) {
    __hip_bfloat16 h = __float2bfloat16(f);   // RNE
    unsigned short r;
    __builtin_memcpy(&r, &h, 2);
    return r;
}
__device__ __forceinline__ float bflo(unsigned u) { return __uint_as_float(u << 16); }
__device__ __forceinline__ float bfhi(unsigned u) { return __uint_as_float(u & 0xffff0000u); }

__device__ __forceinline__ bf16x8 ldfrag(const unsigned short* p) {
    uint4 u = *(const uint4*)p;
    return __builtin_bit_cast(bf16x8, u);
}
// fp32 path vectorized: two float4 loads instead of 8 scalar dword loads
__device__ __forceinline__ bf16x8 ldfrag_any(const void* p, long off, int fp32) {
    if (!fp32) return ldfrag((const unsigned short*)p + off);
    const float4* f = (const float4*)((const float*)p + off);
    float4 u0 = f[0];
    float4 u1 = f[1];
    uint4 u = make_uint4((unsigned)f2bf(u0.x) | ((unsigned)f2bf(u0.y) << 16),
                         (unsigned)f2bf(u0.z) | ((unsigned)f2bf(u0.w) << 16),
                         (unsigned)f2bf(u1.x) | ((unsigned)f2bf(u1.y) << 16),
                         (unsigned)f2bf(u1.z) | ((unsigned)f2bf(u1.w) << 16));
    return __builtin_bit_cast(bf16x8, u);
}

// ---------------- dtype sniffer + static bucket-cursor init ----------------
__global__ __launch_bounds__(512) void k_detect(const void* x, const void* ei, int* flags,
                                                int* __restrict__ bcur, int NB) {
    int t = threadIdx.x;
    for (int b = t; b < NB; b += 512) bcur[b] = b * BKCAP;
    if (t != 0) return;
    const unsigned* xw = (const unsigned*)x;
    int bf16 = 1;
    for (int i = 0; i < 16; ++i) {
        unsigned w = xw[i];
        int elo = (w >> 7) & 0xFF;
        int ehi = (w >> 23) & 0xFF;
        if (elo < 100 || elo > 140 || ehi < 100 || ehi > 140) bf16 = 0;
    }
    const unsigned* iw = (const unsigned*)ei;
    int i64 = 1; unsigned anyev = 0;
    for (int k = 0; k < 8; ++k) {
        if (iw[2 * k + 1] != 0) i64 = 0;
        anyev |= iw[2 * k];
    }
    if (anyev == 0) i64 = 0;
    flags[0] = bf16 ? 0 : 1;
    flags[1] = i64;
}

// ---------------- per-graph segment bounds from sorted batch ----------------
__global__ __launch_bounds__(256) void k_bounds(const void* __restrict__ batch, int N, int G,
                                                int* __restrict__ bounds,
                                                const int* __restrict__ flags) {
    int i64 = flags[1];
    int i = blockIdx.x * 256 + threadIdx.x;
    if (i >= N) return;
    int b = min(max(ldi(batch, i, i64), 0), G - 1);
    int p = (i == 0) ? -1 : min(max(ldi(batch, (long)i - 1, i64), 0), G - 1);
    for (int g = p + 1; g <= b; ++g) bounds[g] = i;
    if (i == N - 1)
        for (int g = b + 1; g <= G; ++g) bounds[g] = N;
}

// ---------------- sort pass A: per-chunk LDS counting sort into static bucket regions ----------------
// Scan: wave-level shfl_up scans (barrier-free) + cross-wave combine.
__global__ __launch_bounds__(512) void k_sortA(const void* __restrict__ ei, int E, int nbuck,
                                               int* bcur, int* __restrict__ bkt,
                                               const int* __restrict__ flags) {
    __shared__ int lbuf[ACAP];
    __shared__ unsigned short lbkt[ACAP];   // slot -> bucket map (no binary search)
    __shared__ int lh[NBMAX];
    __shared__ int lsc[NBMAX];
    __shared__ int lcur[NBMAX];
    __shared__ int gbase[NBMAX];
    __shared__ int wpart[8];
    int i64 = flags[1];
    int t = threadIdx.x;                 // 0..511
    int e0 = blockIdx.x * ACAP;
    int e1 = min(E, e0 + ACAP);
    int cnt = e1 - e0;
    lh[t] = 0;
    __syncthreads();
    for (int e = e0 + t; e < e1; e += 512)
        atomicAdd(&lh[(ldi(ei, (long)E + e, i64) >> 7) & (NBMAX - 1)], 1);
    __syncthreads();
    int v = lh[t];
    int lane = t & 63, wq = t >> 6;
    int incl = v;
#pragma unroll
    for (int off = 1; off < 64; off <<= 1) {
        int n = __shfl_up(incl, off);
        if (lane >= off) incl += n;
    }
    if (lane == 63) wpart[wq] = incl;
    __syncthreads();
    if (t == 0) {
        int acc = 0;
#pragma unroll
        for (int i = 0; i < 8; ++i) { int xx = wpart[i]; wpart[i] = acc; acc += xx; }
    }
    __syncthreads();
    int ex = wpart[wq] + incl - v;       // exclusive prefix
    lsc[t] = ex;
    lcur[t] = ex;
    gbase[t] = (v && t < nbuck) ? atomicAdd(&bcur[t], v) : 0;
    __syncthreads();
    for (int e = e0 + t; e < e1; e += 512) {
        int s = ldi(ei, e, i64);
        int d = ldi(ei, (long)E + e, i64);
        int b = (d >> 7) & (NBMAX - 1);
        int r = atomicAdd(&lcur[b], 1);
        r = min(max(r, 0), ACAP - 1);
        lbuf[r] = (s << 7) | (d & (BW - 1));
        lbkt[r] = (unsigned short)b;
    }
    __syncthreads();
    // coalesced writeout: slot i -> bucket via direct map
    for (int i = t; i < cnt; i += 512) {
        int lo = lbkt[i];
        int idx = gbase[lo] + (i - lsc[lo]);
        if (idx >= lo * BKCAP && idx < (lo + 1) * BKCAP) bkt[idx] = lbuf[i];
    }
}

// ---------------- sort pass B: per-bucket LDS counting sort -> csr, cursor, deg, dinv ----------------
__global__ __launch_bounds__(512) void k_sortB(const int* __restrict__ bkt,
                                               const int* __restrict__ bcur,
                                               int N,
                                               int* __restrict__ csr,
                                               int* __restrict__ cursor,
                                               int* __restrict__ deg,
                                               float* __restrict__ dinv) {
    __shared__ int lstage[BKCAP];       // 20 KB
    __shared__ int lcsr[BKCAP];         // 20 KB
    __shared__ int lh[BW], lsc[BW], lcur[BW];
    int b = blockIdx.x, t = threadIdx.x;
    int base = b * BKCAP;
    int cnt = min(max(bcur[b] - base, 0), BKCAP);
    if (t < BW) lh[t] = 0;
    __syncthreads();
    for (int i = t; i < cnt; i += 512) {
        int w = __builtin_nontemporal_load(&bkt[base + i]);
        lstage[i] = w;
        atomicAdd(&lh[w & (BW - 1)], 1);
    }
    __syncthreads();
    if (t < BW) lsc[t] = lh[t];
    __syncthreads();
    for (int off = 1; off < BW; off <<= 1) {
        int a = (t < BW && t >= off) ? lsc[t - off] : 0;
        __syncthreads();
        if (t < BW) lsc[t] += a;
        __syncthreads();
    }
    if (t < BW) {
        int ex = lsc[t] - lh[t];
        lcur[t] = ex;
        int n = b * BW + t;
        if (n < N) {
            cursor[n] = base + ex;
            deg[n] = lh[t];
            dinv[n] = rsqrtf((float)(lh[t] + 1));   // +1 self-loop
        }
    }
    __syncthreads();
    for (int i = t; i < cnt; i += 512) {
        int w = lstage[i];
        int r = atomicAdd(&lcur[w & (BW - 1)], 1);
        int sv = (int)((unsigned)w >> 7);
        if (sv >= N) sv = 0;                        // poison guard
        r = min(max(r, 0), BKCAP - 1);
        lcsr[r] = sv;
    }
    __syncthreads();
    for (int i = t; i < cnt; i += 512) csr[base + i] = lcsr[i];
}

// ---------------- GEMM1 (MFMA): t[i,:] = bf16(dinv[i] * (x[i,:] @ W1)) ----------------
// Output is PLANE-SPLIT: plane p (p = col>>5) lives at t + p*N*32, row stride 32.
// 128 rows per block (W staging amortized 2x).
__global__ __launch_bounds__(256) void k_gemm1(const void* __restrict__ x,
                                               const void* __restrict__ W,
                                               const float* __restrict__ dinv,
                                               unsigned short* __restrict__ t, int N,
                                               const int* __restrict__ flags) {
    __shared__ __align__(16) unsigned short wt[HID * W1STR];   // W1^T, padded
    int fp32 = flags[0];
    int tid = threadIdx.x;
    size_t N32 = (size_t)N * 32;
    if (fp32) {
        const float* wf = (const float*)W;
        for (int i = tid * 4; i < F_IN * HID; i += 1024) {
            float4 w4 = *(const float4*)(wf + i);
            int k = i >> 6, n = i & 63;
            wt[(n + 0) * W1STR + k] = f2bf(w4.x);
            wt[(n + 1) * W1STR + k] = f2bf(w4.y);
            wt[(n + 2) * W1STR + k] = f2bf(w4.z);
            wt[(n + 3) * W1STR + k] = f2bf(w4.w);
        }
    } else {
        for (int i = tid; i < F_IN * HID; i += 256) {
            int k = i >> 6, n = i & 63;
            wt[n * W1STR + k] = f2bf(ldf(W, i, 0));
        }
    }
    __syncthreads();
    int wv = tid >> 6, lane = tid & 63;
    int quad = lane >> 4, l16 = lane & 15;
#pragma unroll
    for (int rr = 0; rr < 128; rr += 64) {
        int r0 = blockIdx.x * 128 + rr + wv * 16;
        if (r0 >= N) break;
        int rowA = min(r0 + l16, N - 1);
        bf16x8 a[4];
#pragma unroll
        for (int kq = 0; kq < 4; ++kq)
            a[kq] = ldfrag_any(x, (long)rowA * F_IN + kq * 32 + quad * 8, fp32);
        float di[4];
        int rowC = r0 + quad * 4;
#pragma unroll
        for (int r = 0; r < 4; ++r) di[r] = (rowC + r < N) ? dinv[rowC + r] : 0.f;
#pragma unroll
        for (int cg = 0; cg < 4; ++cg) {
            int col = cg * 16 + l16;
            f32x4 acc = {0.f, 0.f, 0.f, 0.f};
#pragma unroll
            for (int kq = 0; kq < 4; ++kq) {
                bf16x8 b = ldfrag(wt + col * W1STR + kq * 32 + quad * 8);
                acc = __builtin_amdgcn_mfma_f32_16x16x32_bf16(a[kq], b, acc, 0, 0, 0);
            }
            unsigned short* tp = t + (size_t)(col >> 5) * N32 + (col & 31);
#pragma unroll
            for (int r = 0; r < 4; ++r) {
                int row = rowC + r;
                if (row < N) tp[(size_t)row * 32] = f2bf(di[r] * acc[r]);
            }
        }
    }
}

// ---------------- GEMM2 (MFMA): t2 = bf16(dinv * (h @ W2)), h bf16 plane-split ----------------
__global__ __launch_bounds__(256) void k_gemm2(const unsigned short* __restrict__ h,
                                               const void* __restrict__ W,
                                               const float* __restrict__ dinv,
                                               unsigned short* __restrict__ t, int N,
                                               const int* __restrict__ flags) {
    __shared__ __align__(16) unsigned short wt[HID * W2STR];   // W2^T, padded
    int fp32 = flags[0];
    int tid = threadIdx.x;
    size_t N32 = (size_t)N * 32;
    if (fp32) {
        const float* wf = (const float*)W;
        for (int i = tid * 4; i < HID * HID; i += 1024) {
            float4 w4 = *(const float4*)(wf + i);
            int k = i >> 6, n = i & 63;
            wt[(n + 0) * W2STR + k] = f2bf(w4.x);
            wt[(n + 1) * W2STR + k] = f2bf(w4.y);
            wt[(n + 2) * W2STR + k] = f2bf(w4.z);
            wt[(n + 3) * W2STR + k] = f2bf(w4.w);
        }
    } else {
        for (int i = tid; i < HID * HID; i += 256) {
            int k = i >> 6, n = i & 63;
            wt[n * W2STR + k] = f2bf(ldf(W, i, 0));
        }
    }
    __syncthreads();
    int wv = tid >> 6, lane = tid & 63;
    int quad = lane >> 4, l16 = lane & 15;
#pragma unroll
    for (int rr = 0; rr < 128; rr += 64) {
        int r0 = blockIdx.x * 128 + rr + wv * 16;
        if (r0 >= N) break;
        int rowA = min(r0 + l16, N - 1);
        bf16x8 a[2];
#pragma unroll
        for (int kq = 0; kq < 2; ++kq)   // kq = input-feature plane
            a[kq] = ldfrag(h + (size_t)kq * N32 + (size_t)rowA * 32 + quad * 8);
        float di[4];
        int rowC = r0 + quad * 4;
#pragma unroll
        for (int r = 0; r < 4; ++r) di[r] = (rowC + r < N) ? dinv[rowC + r] : 0.f;
#pragma unroll
        for (int cg = 0; cg < 4; ++cg) {
            int col = cg * 16 + l16;
            f32x4 acc = {0.f, 0.f, 0.f, 0.f};
#pragma unroll
            for (int kq = 0; kq < 2; ++kq) {
                bf16x8 b = ldfrag(wt + col * W2STR + kq * 32 + quad * 8);
                acc = __builtin_amdgcn_mfma_f32_16x16x32_bf16(a[kq], b, acc, 0, 0, 0);
            }
            unsigned short* tp = t + (size_t)(col >> 5) * N32 + (col & 31);
#pragma unroll
            for (int r = 0; r < 4; ++r) {
                int row = rowC + r;
                if (row < N) tp[(size_t)row * 32] = f2bf(di[r] * acc[r]);
            }
        }
    }
}

// ---------------- aggregation: two L2-RESIDENT passes over 3.2MB feature planes ----------------
// The 6.4MB message table doesn't fit a 4MiB per-XCD L2 (round-0: FETCH = 8 XCDs x table).
// Planes are PHYSICALLY segregated (N*32 each) so cache lines never straddle halves;
// each pass gathers 64B rows from one plane -> fully L2-resident.
// 2 nodes/wave, 4 slots x 8 feature-lanes x uint2; 16 outstanding gathers/wave.
template <bool RELU, int FH>
__global__ __launch_bounds__(256) void k_agg(const unsigned short* __restrict__ t,
                                             const int* __restrict__ csr,
                                             const int* __restrict__ cursor,
                                             const int* __restrict__ deg,
                                             const float* __restrict__ dinv,
                                             const void* __restrict__ bias,
                                             unsigned short* __restrict__ out,
                                             int N, int SZ, const int* __restrict__ flags) {
    __shared__ float sbias[32];
    __shared__ int scur[8];
    __shared__ int sdeg[8];
    __shared__ float sdv[8];
    int tid = threadIdx.x;
    int nb = blockIdx.x * 8;
    if (tid < 32) sbias[tid] = ldf(bias, FH * 32 + tid, flags[0]);
    if (tid >= 64 && tid < 72) {
        int q = tid - 64;
        int node = nb + q;
        int c = 0, d = 0;
        float dv = 0.f;
        if (node < N) { c = cursor[node]; d = deg[node]; dv = dinv[node]; }
        scur[q] = c; sdeg[q] = d; sdv[q] = dv;
    }
    __syncthreads();
    size_t N32 = (size_t)N * 32;
    const unsigned short* tb = t + (size_t)FH * N32;    // this pass's plane
    unsigned short* ob = out + (size_t)FH * N32;
    int wv = tid >> 6, lane = tid & 63;
    int half = lane >> 5;               // node within wave
    int idx = wv * 2 + half;            // node within block (0..7)
    int node = nb + idx;
    int l = lane & 31;
    int g = l >> 3;                     // neighbor slot 0..3
    int l4 = (l & 7) * 4;               // this lane's 4 features (within the plane)
    bool alive = (node < N);
    int snode = alive ? node : 0;
    int beg = scur[idx];
    int dg = sdeg[idx];
    beg = min(max(beg, 0), SZ);
    int end = beg + min(max(dg, 0), SZ - beg);
    // early self-loop fetch (overlaps with the gather loop)
    uint2 sv = make_uint2(0u, 0u);
    if (g == 0) sv = *(const uint2*)(tb + (size_t)snode * 32 + l4);
    float a0 = 0.f, a1 = 0.f, a2 = 0.f, a3 = 0.f;
    int e = beg;
    // ---- full 32-edge blocks: unconditional ----
    for (; e + 32 <= end; e += 32) {
        int s[8];
#pragma unroll
        for (int k = 0; k < 8; ++k) {
            int si = __builtin_nontemporal_load(&csr[e + 4 * k + g]);
            s[k] = ((unsigned)si < (unsigned)N) ? si : 0;
        }
        uint2 v[8];
#pragma unroll
        for (int k = 0; k < 8; ++k)
            v[k] = *(const uint2*)(tb + (size_t)s[k] * 32 + l4);
#pragma unroll
        for (int k = 0; k < 8; ++k) {
            a0 += bflo(v[k].x); a1 += bfhi(v[k].x);
            a2 += bflo(v[k].y); a3 += bfhi(v[k].y);
        }
    }
    // ---- tail (<32 edges): single masked block ----
    if (e < end) {
        int s[8];
#pragma unroll
        for (int k = 0; k < 8; ++k) {
            int i = e + 4 * k + g;
            int si = __builtin_nontemporal_load(&csr[i < end ? i : end - 1]);
            s[k] = ((unsigned)si < (unsigned)N) ? si : 0;
        }
        uint2 v[8];
#pragma unroll
        for (int k = 0; k < 8; ++k)
            v[k] = *(const uint2*)(tb + (size_t)s[k] * 32 + l4);
#pragma unroll
        for (int k = 0; k < 8; ++k) {
            if (e + 4 * k + g < end) {
                a0 += bflo(v[k].x); a1 += bfhi(v[k].x);
                a2 += bflo(v[k].y); a3 += bfhi(v[k].y);
            }
        }
    }
    // reduce across the 4 neighbor slots (stays within the 32-lane half)
#pragma unroll
    for (int m = 8; m <= 16; m <<= 1) {
        a0 += __shfl_xor(a0, m); a1 += __shfl_xor(a1, m);
        a2 += __shfl_xor(a2, m); a3 += __shfl_xor(a3, m);
    }
    if (g == 0 && alive) {
        // self-loop
        a0 += bflo(sv.x); a1 += bfhi(sv.x); a2 += bflo(sv.y); a3 += bfhi(sv.y);
        float di = sdv[idx];
        float v0 = di * a0 + sbias[l4 + 0];
        float v1 = di * a1 + sbias[l4 + 1];
        float v2 = di * a2 + sbias[l4 + 2];
        float v3 = di * a3 + sbias[l4 + 3];
        if (RELU) {
            v0 = fmaxf(v0, 0.f); v1 = fmaxf(v1, 0.f);
            v2 = fmaxf(v2, 0.f); v3 = fmaxf(v3, 0.f);
        }
        uint2 pk;
        pk.x = (unsigned)f2bf(v0) | ((unsigned)f2bf(v1) << 16);
        pk.y = (unsigned)f2bf(v2) | ((unsigned)f2bf(v3) << 16);
        *(uint2*)(ob + (size_t)node * 32 + l4) = pk;
    }
}

// ---------------- fused mean-pool + head (4 waves per graph; h2 plane-split) ----------------
__global__ __launch_bounds__(256) void k_poolout(const unsigned short* __restrict__ h2,
                                                 const int* __restrict__ bounds, int N,
                                                 const void* __restrict__ Wout,
                                                 const void* __restrict__ bout,
                                                 void* __restrict__ out,
                                                 const int* __restrict__ flags) {
    __shared__ float pr[HID];
    __shared__ float sacc[4][HID];
    int g = blockIdx.x;
    int start = min(max(bounds[g], 0), N);
    int endg = min(max(bounds[g + 1], start), N);
    int tid = threadIdx.x;
    int wv = tid >> 6, lane = tid & 63;
    int half = lane >> 5;
    int l = lane & 31;                  // column pair index: cols 2l, 2l+1
    size_t N32 = (size_t)N * 32;
    const unsigned short* hb = h2 + (size_t)(l >> 4) * N32 + 2 * (l & 15);
    float s0 = 0.f, s1 = 0.f;
    for (int r = start + wv * 2 + half; r < endg; r += 8) {
        unsigned u = *(const unsigned*)(hb + (size_t)r * 32);
        s0 += bflo(u);
        s1 += bfhi(u);
    }
    s0 += __shfl_xor(s0, 32);
    s1 += __shfl_xor(s1, 32);
    if (lane < 32) {
        sacc[wv][2 * l] = s0;
        sacc[wv][2 * l + 1] = s1;
    }
    __syncthreads();
    if (tid < HID) {
        float inv = 1.f / fmaxf((float)(endg - start), 1.f);
        pr[tid] = (sacc[0][tid] + sacc[1][tid] + sacc[2][tid] + sacc[3][tid]) * inv;
    }
    __syncthreads();
    int fp32 = flags[0];
    if (tid < NCLS) {
        float acc = ldf(bout, tid, fp32);
#pragma unroll 4
        for (int k = 0; k < HID; ++k)
            acc += pr[k] * ldf(Wout, k * NCLS + tid, fp32);
        if (fp32) ((float*)out)[g * NCLS + tid] = acc;
        else ((__hip_bfloat16*)out)[g * NCLS + tid] = __float2bfloat16(acc);
    }
}

extern "C" void kernel_launch(void* const* d_in, const int* in_sizes, int n_in,
                              void* d_out, int out_size, void* d_ws, size_t ws_size,
                              hipStream_t stream) {
    const void* x    = d_in[0];
    const void* ei   = d_in[1];
    const void* bat  = d_in[2];
    const void* W1   = d_in[3];
    const void* b1   = d_in[4];
    const void* W2   = d_in[5];
    const void* b2   = d_in[6];
    const void* Wout = d_in[7];
    const void* bout = d_in[8];

    const int N = in_sizes[0] / F_IN;
    const int E = in_sizes[1] / 2;
    const int G = out_size / NCLS;
    const int NB = (N + BW - 1) / BW;   // < NBMAX
    const int SZ = NB * BKCAP;          // padded csr/bkt length

    char* ws = (char*)d_ws;
    size_t off = 0;
    auto carve = [&](size_t bytes) -> void* {
        void* p = ws + off;
        off = (off + bytes + 255) & ~(size_t)255;
        return p;
    };
    int*            flags  = (int*)carve(64);
    int*            deg    = (int*)carve((size_t)N * 4);
    int*            cursor = (int*)carve((size_t)N * 4);
    float*          dinv   = (float*)carve((size_t)N * 4);
    int*            bcur   = (int*)carve((size_t)NB * 4);
    int*            bounds = (int*)carve((size_t)(G + 1) * 4);
    int*            csr    = (int*)carve((size_t)SZ * 4);
    int*            bkt    = (int*)carve((size_t)SZ * 4);
    unsigned short* t      = (unsigned short*)carve((size_t)N * HID * 2);  // t1/t2, plane-split
    unsigned short* h      = (unsigned short*)carve((size_t)N * HID * 2);  // h1/h2, plane-split
    (void)ws_size; (void)n_in;

    // sniff dtypes + init static bucket cursors
    k_detect<<<1, 512, 0, stream>>>(x, ei, flags, bcur, NB);
    // per-graph segment bounds (needs flags)
    k_bounds<<<(N + 255) / 256, 256, 0, stream>>>(bat, N, G, bounds, flags);

    // CSR build
    int na = (E + ACAP - 1) / ACAP;
    k_sortA<<<na, 512, 0, stream>>>(ei, E, NB, bcur, bkt, flags);
    k_sortB<<<NB, 512, 0, stream>>>(bkt, bcur, N, csr, cursor, deg, dinv);

    int gb = (N + 127) / 128;
    int ab = (N + 7) / 8;
    // layer 1
    k_gemm1<<<gb, 256, 0, stream>>>(x, W1, dinv, t, N, flags);
    k_agg<true, 0><<<ab, 256, 0, stream>>>(t, csr, cursor, deg, dinv, b1, h, N, SZ, flags);
    k_agg<true, 1><<<ab, 256, 0, stream>>>(t, csr, cursor, deg, dinv, b1, h, N, SZ, flags);
    // layer 2
    k_gemm2<<<gb, 256, 0, stream>>>(h, W2, dinv, t, N, flags);   // t now holds t2
    k_agg<false, 0><<<ab, 256, 0, stream>>>(t, csr, cursor, deg, dinv, b2, h, N, SZ, flags);
    k_agg<false, 1><<<ab, 256, 0, stream>>>(t, csr, cursor, deg, dinv, b2, h, N, SZ, flags);
    // fused pool + head
    k_poolout<<<G, 256, 0, stream>>>(h, bounds, N, Wout, bout, d_out, flags);
}

// Round 4
// 207.483 us; speedup vs baseline: 1.1420x; 1.1420x over previous
//
#include <hip/hip_runtime.h>
#include <hip/hip_bf16.h>

#define F_IN 128
#define HID  64
#define NCLS 19
#define BW   128          // nodes per bucket (dst >> 7)
#define NBMAX 512         // max buckets (N <= 65536); also sortA scan width
#define ACAP 3072         // edges per k_sortA block (12 KB lbuf; ~2 blocks/CU co-resident)
#define BKCAP 5120        // static per-bucket capacity (mean 4096, sigma 64 -> 16-sigma safe)
#define W1STR 136         // padded LDS stride (shorts) for W1^T rows
#define W2STR 72          // padded LDS stride (shorts) for W2^T rows

typedef __bf16 bf16x8 __attribute__((ext_vector_type(8)));
typedef float  f32x4  __attribute__((ext_vector_type(4)));

// -------- adaptive loads: flags[0]=1 -> floats are fp32 (else bf16)
//          flags[1]=1 -> indices are int64 (else int32)
__device__ __forceinline__ float ldf(const void* p, long i, int fp32) {
    if (fp32) return ((const float*)p)[i];
    return __bfloat162float(((const __hip_bfloat16*)p)[i]);
}
__device__ __forceinline__ int ldi(const void* p, long i, int i64) {
    if (i64) return (int)((const long long*)p)[i];
    return ((const int*)p)[i];
}
__device__ __forceinline__ unsigned short f2bf(float f) {
    __hip_bfloat16 h = __float2bfloat16(f);   // RNE
    unsigned short r;
    __builtin_memcpy(&r, &h, 2);
    return r;
}
__device__ __forceinline__ float bflo(unsigned u) { return __uint_as_float(u << 16); }
__device__ __forceinline__ float bfhi(unsigned u) { return __uint_as_float(u & 0xffff0000u); }

__device__ __forceinline__ bf16x8 ldfrag(const unsigned short* p) {
    uint4 u = *(const uint4*)p;
    return __builtin_bit_cast(bf16x8, u);
}
// fp32 path vectorized: two float4 loads instead of 8 scalar dword loads
__device__ __forceinline__ bf16x8 ldfrag_any(const void* p, long off, int fp32) {
    if (!fp32) return ldfrag((const unsigned short*)p + off);
    const float4* f = (const float4*)((const float*)p + off);
    float4 u0 = f[0];
    float4 u1 = f[1];
    uint4 u = make_uint4((unsigned)f2bf(u0.x) | ((unsigned)f2bf(u0.y) << 16),
                         (unsigned)f2bf(u0.z) | ((unsigned)f2bf(u0.w) << 16),
                         (unsigned)f2bf(u1.x) | ((unsigned)f2bf(u1.y) << 16),
                         (unsigned)f2bf(u1.z) | ((unsigned)f2bf(u1.w) << 16));
    return __builtin_bit_cast(bf16x8, u);
}

// ---------------- dtype sniffer + static bucket-cursor init ----------------
__global__ __launch_bounds__(512) void k_detect(const void* x, const void* ei, int* flags,
                                                int* __restrict__ bcur, int NB) {
    int t = threadIdx.x;
    for (int b = t; b < NB; b += 512) bcur[b] = b * BKCAP;
    if (t != 0) return;
    const unsigned* xw = (const unsigned*)x;
    int bf16 = 1;
    for (int i = 0; i < 16; ++i) {
        unsigned w = xw[i];
        int elo = (w >> 7) & 0xFF;
        int ehi = (w >> 23) & 0xFF;
        if (elo < 100 || elo > 140 || ehi < 100 || ehi > 140) bf16 = 0;
    }
    const unsigned* iw = (const unsigned*)ei;
    int i64 = 1; unsigned anyev = 0;
    for (int k = 0; k < 8; ++k) {
        if (iw[2 * k + 1] != 0) i64 = 0;
        anyev |= iw[2 * k];
    }
    if (anyev == 0) i64 = 0;
    flags[0] = bf16 ? 0 : 1;
    flags[1] = i64;
}

// ---------------- per-graph segment bounds from sorted batch ----------------
__global__ __launch_bounds__(256) void k_bounds(const void* __restrict__ batch, int N, int G,
                                                int* __restrict__ bounds,
                                                const int* __restrict__ flags) {
    int i64 = flags[1];
    int i = blockIdx.x * 256 + threadIdx.x;
    if (i >= N) return;
    int b = min(max(ldi(batch, i, i64), 0), G - 1);
    int p = (i == 0) ? -1 : min(max(ldi(batch, (long)i - 1, i64), 0), G - 1);
    for (int g = p + 1; g <= b; ++g) bounds[g] = i;
    if (i == N - 1)
        for (int g = b + 1; g <= G; ++g) bounds[g] = N;
}

// ---------------- sort pass A: per-chunk LDS counting sort into static bucket regions ----------------
// Scan: wave-level shfl_up scans (barrier-free) + cross-wave combine.
__global__ __launch_bounds__(512) void k_sortA(const void* __restrict__ ei, int E, int nbuck,
                                               int* bcur, int* __restrict__ bkt,
                                               const int* __restrict__ flags) {
    __shared__ int lbuf[ACAP];
    __shared__ unsigned short lbkt[ACAP];   // slot -> bucket map (no binary search)
    __shared__ int lh[NBMAX];
    __shared__ int lsc[NBMAX];
    __shared__ int lcur[NBMAX];
    __shared__ int gbase[NBMAX];
    __shared__ int wpart[8];
    int i64 = flags[1];
    int t = threadIdx.x;                 // 0..511
    int e0 = blockIdx.x * ACAP;
    int e1 = min(E, e0 + ACAP);
    int cnt = e1 - e0;
    lh[t] = 0;
    __syncthreads();
    for (int e = e0 + t; e < e1; e += 512)
        atomicAdd(&lh[(ldi(ei, (long)E + e, i64) >> 7) & (NBMAX - 1)], 1);
    __syncthreads();
    int v = lh[t];
    int lane = t & 63, wq = t >> 6;
    int incl = v;
#pragma unroll
    for (int off = 1; off < 64; off <<= 1) {
        int n = __shfl_up(incl, off);
        if (lane >= off) incl += n;
    }
    if (lane == 63) wpart[wq] = incl;
    __syncthreads();
    if (t == 0) {
        int acc = 0;
#pragma unroll
        for (int i = 0; i < 8; ++i) { int xx = wpart[i]; wpart[i] = acc; acc += xx; }
    }
    __syncthreads();
    int ex = wpart[wq] + incl - v;       // exclusive prefix
    lsc[t] = ex;
    lcur[t] = ex;
    gbase[t] = (v && t < nbuck) ? atomicAdd(&bcur[t], v) : 0;
    __syncthreads();
    for (int e = e0 + t; e < e1; e += 512) {
        int s = ldi(ei, e, i64);
        int d = ldi(ei, (long)E + e, i64);
        int b = (d >> 7) & (NBMAX - 1);
        int r = atomicAdd(&lcur[b], 1);
        r = min(max(r, 0), ACAP - 1);
        lbuf[r] = (s << 7) | (d & (BW - 1));
        lbkt[r] = (unsigned short)b;
    }
    __syncthreads();
    // coalesced writeout: slot i -> bucket via direct map
    for (int i = t; i < cnt; i += 512) {
        int lo = lbkt[i];
        int idx = gbase[lo] + (i - lsc[lo]);
        if (idx >= lo * BKCAP && idx < (lo + 1) * BKCAP) bkt[idx] = lbuf[i];
    }
}

// ---------------- sort pass B: per-bucket LDS counting sort -> csr, cursor, deg, dinv ----------------
__global__ __launch_bounds__(512) void k_sortB(const int* __restrict__ bkt,
                                               const int* __restrict__ bcur,
                                               int N,
                                               int* __restrict__ csr,
                                               int* __restrict__ cursor,
                                               int* __restrict__ deg,
                                               float* __restrict__ dinv) {
    __shared__ int lstage[BKCAP];       // 20 KB
    __shared__ int lcsr[BKCAP];         // 20 KB
    __shared__ int lh[BW], lsc[BW], lcur[BW];
    int b = blockIdx.x, t = threadIdx.x;
    int base = b * BKCAP;
    int cnt = min(max(bcur[b] - base, 0), BKCAP);
    if (t < BW) lh[t] = 0;
    __syncthreads();
    for (int i = t; i < cnt; i += 512) {
        int w = __builtin_nontemporal_load(&bkt[base + i]);
        lstage[i] = w;
        atomicAdd(&lh[w & (BW - 1)], 1);
    }
    __syncthreads();
    if (t < BW) lsc[t] = lh[t];
    __syncthreads();
    for (int off = 1; off < BW; off <<= 1) {
        int a = (t < BW && t >= off) ? lsc[t - off] : 0;
        __syncthreads();
        if (t < BW) lsc[t] += a;
        __syncthreads();
    }
    if (t < BW) {
        int ex = lsc[t] - lh[t];
        lcur[t] = ex;
        int n = b * BW + t;
        if (n < N) {
            cursor[n] = base + ex;
            deg[n] = lh[t];
            dinv[n] = rsqrtf((float)(lh[t] + 1));   // +1 self-loop
        }
    }
    __syncthreads();
    for (int i = t; i < cnt; i += 512) {
        int w = lstage[i];
        int r = atomicAdd(&lcur[w & (BW - 1)], 1);
        int sv = (int)((unsigned)w >> 7);
        if (sv >= N) sv = 0;                        // poison guard
        r = min(max(r, 0), BKCAP - 1);
        lcsr[r] = sv;
    }
    __syncthreads();
    for (int i = t; i < cnt; i += 512) csr[base + i] = lcsr[i];
}

// ---------------- GEMM1 (MFMA): t[i,:] = bf16(dinv[i] * (x[i,:] @ W1)) ----------------
__global__ __launch_bounds__(256) void k_gemm1(const void* __restrict__ x,
                                               const void* __restrict__ W,
                                               const float* __restrict__ dinv,
                                               unsigned short* __restrict__ t, int N,
                                               const int* __restrict__ flags) {
    __shared__ __align__(16) unsigned short wt[HID * W1STR];   // W1^T, padded
    int fp32 = flags[0];
    int tid = threadIdx.x;
    // coalesced staging: read W row-major (vectorized on fp32 path), write LDS transposed
    if (fp32) {
        const float* wf = (const float*)W;
        for (int i = tid * 4; i < F_IN * HID; i += 1024) {
            float4 w4 = *(const float4*)(wf + i);
            int k = i >> 6, n = i & 63;
            wt[(n + 0) * W1STR + k] = f2bf(w4.x);
            wt[(n + 1) * W1STR + k] = f2bf(w4.y);
            wt[(n + 2) * W1STR + k] = f2bf(w4.z);
            wt[(n + 3) * W1STR + k] = f2bf(w4.w);
        }
    } else {
        for (int i = tid; i < F_IN * HID; i += 256) {
            int k = i >> 6, n = i & 63;
            wt[n * W1STR + k] = f2bf(ldf(W, i, 0));
        }
    }
    __syncthreads();
    int wv = tid >> 6, lane = tid & 63;
    int quad = lane >> 4, l16 = lane & 15;
    int r0 = blockIdx.x * 64 + wv * 16;
    int rowA = min(r0 + l16, N - 1);
    bf16x8 a[4];
#pragma unroll
    for (int kq = 0; kq < 4; ++kq)
        a[kq] = ldfrag_any(x, (long)rowA * F_IN + kq * 32 + quad * 8, fp32);
    float di[4];
    int rowC = r0 + quad * 4;
#pragma unroll
    for (int r = 0; r < 4; ++r) di[r] = (rowC + r < N) ? dinv[rowC + r] : 0.f;
#pragma unroll
    for (int cg = 0; cg < 4; ++cg) {
        int col = cg * 16 + l16;
        f32x4 acc = {0.f, 0.f, 0.f, 0.f};
#pragma unroll
        for (int kq = 0; kq < 4; ++kq) {
            bf16x8 b = ldfrag(wt + col * W1STR + kq * 32 + quad * 8);
            acc = __builtin_amdgcn_mfma_f32_16x16x32_bf16(a[kq], b, acc, 0, 0, 0);
        }
#pragma unroll
        for (int r = 0; r < 4; ++r) {
            int row = rowC + r;
            if (row < N) t[(size_t)row * HID + col] = f2bf(di[r] * acc[r]);
        }
    }
}

// ---------------- GEMM2 (MFMA): t2[i,:] = bf16(dinv[i] * (h[i,:] @ W2)), h bf16 ----------------
__global__ __launch_bounds__(256) void k_gemm2(const unsigned short* __restrict__ h,
                                               const void* __restrict__ W,
                                               const float* __restrict__ dinv,
                                               unsigned short* __restrict__ t, int N,
                                               const int* __restrict__ flags) {
    __shared__ __align__(16) unsigned short wt[HID * W2STR];   // W2^T, padded
    int fp32 = flags[0];
    int tid = threadIdx.x;
    // coalesced staging: read W row-major (vectorized on fp32 path), write LDS transposed
    if (fp32) {
        const float* wf = (const float*)W;
        for (int i = tid * 4; i < HID * HID; i += 1024) {
            float4 w4 = *(const float4*)(wf + i);
            int k = i >> 6, n = i & 63;
            wt[(n + 0) * W2STR + k] = f2bf(w4.x);
            wt[(n + 1) * W2STR + k] = f2bf(w4.y);
            wt[(n + 2) * W2STR + k] = f2bf(w4.z);
            wt[(n + 3) * W2STR + k] = f2bf(w4.w);
        }
    } else {
        for (int i = tid; i < HID * HID; i += 256) {
            int k = i >> 6, n = i & 63;
            wt[n * W2STR + k] = f2bf(ldf(W, i, 0));
        }
    }
    __syncthreads();
    int wv = tid >> 6, lane = tid & 63;
    int quad = lane >> 4, l16 = lane & 15;
    int r0 = blockIdx.x * 64 + wv * 16;
    int rowA = min(r0 + l16, N - 1);
    bf16x8 a[2];
#pragma unroll
    for (int kq = 0; kq < 2; ++kq)
        a[kq] = ldfrag(h + (size_t)rowA * HID + kq * 32 + quad * 8);
    float di[4];
    int rowC = r0 + quad * 4;
#pragma unroll
    for (int r = 0; r < 4; ++r) di[r] = (rowC + r < N) ? dinv[rowC + r] : 0.f;
#pragma unroll
    for (int cg = 0; cg < 4; ++cg) {
        int col = cg * 16 + l16;
        f32x4 acc = {0.f, 0.f, 0.f, 0.f};
#pragma unroll
        for (int kq = 0; kq < 2; ++kq) {
            bf16x8 b = ldfrag(wt + col * W2STR + kq * 32 + quad * 8);
            acc = __builtin_amdgcn_mfma_f32_16x16x32_bf16(a[kq], b, acc, 0, 0, 0);
        }
#pragma unroll
        for (int r = 0; r < 4; ++r) {
            int row = rowC + r;
            if (row < N) t[(size_t)row * HID + col] = f2bf(di[r] * acc[r]);
        }
    }
}

// ---------------- aggregation: 2 nodes per wave, 8 outstanding gathers per node ----------------
// Round-2 structure (best measured) with PACKED accumulation: f32x4 accumulators let the
// compiler emit v_pk_add_f32 (2 adds/instr), cutting per-uint4 VALU 16 -> 12.
template <bool RELU>
__global__ __launch_bounds__(256) void k_agg(const unsigned short* __restrict__ t,
                                             const int* __restrict__ csr,
                                             const int* __restrict__ cursor,
                                             const int* __restrict__ deg,
                                             const float* __restrict__ dinv,
                                             const void* __restrict__ bias,
                                             unsigned short* __restrict__ out,
                                             int N, int SZ, const int* __restrict__ flags) {
    __shared__ float sbias[HID];
    __shared__ int scur[8];
    __shared__ int sdeg[8];
    __shared__ float sdv[8];
    int tid = threadIdx.x;
    int nb = blockIdx.x * 8;
    if (tid < HID) sbias[tid] = ldf(bias, tid, flags[0]);
    if (tid >= 64 && tid < 72) {
        int q = tid - 64;
        int node = nb + q;
        int c = 0, d = 0;
        float dv = 0.f;
        if (node < N) { c = cursor[node]; d = deg[node]; dv = dinv[node]; }
        scur[q] = c; sdeg[q] = d; sdv[q] = dv;
    }
    __syncthreads();
    int wv = tid >> 6, lane = tid & 63;
    int half = lane >> 5;               // node within wave
    int idx = wv * 2 + half;            // node within block (0..7)
    int node = nb + idx;
    int l = lane & 31;
    int g = l >> 3;                     // neighbor slot 0..3
    int l8 = (l & 7) * 8;               // this lane's 8 features
    bool alive = (node < N);
    int snode = alive ? node : 0;
    int beg = scur[idx];
    int dg = sdeg[idx];
    beg = min(max(beg, 0), SZ);
    int end = beg + min(max(dg, 0), SZ - beg);
    // early self-loop fetch (overlaps with the gather loop)
    uint4 sv = make_uint4(0u, 0u, 0u, 0u);
    if (g == 0) sv = *(const uint4*)(t + (size_t)snode * HID + l8);
    f32x4 A = {0.f, 0.f, 0.f, 0.f};     // features l8+0..3
    f32x4 B = {0.f, 0.f, 0.f, 0.f};     // features l8+4..7
    int e = beg;
    // ---- full 32-edge blocks: unconditional ----
    for (; e + 32 <= end; e += 32) {
        int s[8];
#pragma unroll
        for (int k = 0; k < 8; ++k) {
            int si = __builtin_nontemporal_load(&csr[e + 4 * k + g]);
            s[k] = ((unsigned)si < (unsigned)N) ? si : 0;
        }
        uint4 v[8];
#pragma unroll
        for (int k = 0; k < 8; ++k)
            v[k] = *(const uint4*)(t + (size_t)s[k] * HID + l8);
#pragma unroll
        for (int k = 0; k < 8; ++k) {
            f32x4 lo = {bflo(v[k].x), bfhi(v[k].x), bflo(v[k].y), bfhi(v[k].y)};
            f32x4 hi = {bflo(v[k].z), bfhi(v[k].z), bflo(v[k].w), bfhi(v[k].w)};
            A += lo;
            B += hi;
        }
    }
    // ---- tail (<32 edges): single masked block ----
    if (e < end) {
        int s[8];
#pragma unroll
        for (int k = 0; k < 8; ++k) {
            int i = e + 4 * k + g;
            int si = __builtin_nontemporal_load(&csr[i < end ? i : end - 1]);
            s[k] = ((unsigned)si < (unsigned)N) ? si : 0;
        }
        uint4 v[8];
#pragma unroll
        for (int k = 0; k < 8; ++k)
            v[k] = *(const uint4*)(t + (size_t)s[k] * HID + l8);
#pragma unroll
        for (int k = 0; k < 8; ++k) {
            if (e + 4 * k + g < end) {
                f32x4 lo = {bflo(v[k].x), bfhi(v[k].x), bflo(v[k].y), bfhi(v[k].y)};
                f32x4 hi = {bflo(v[k].z), bfhi(v[k].z), bflo(v[k].w), bfhi(v[k].w)};
                A += lo;
                B += hi;
            }
        }
    }
    // reduce across the 4 neighbor slots (stays within the 32-lane half)
#pragma unroll
    for (int m = 8; m <= 16; m <<= 1) {
#pragma unroll
        for (int c = 0; c < 4; ++c) {
            A[c] += __shfl_xor(A[c], m);
            B[c] += __shfl_xor(B[c], m);
        }
    }
    if (g == 0 && alive) {
        // self-loop
        f32x4 slo = {bflo(sv.x), bfhi(sv.x), bflo(sv.y), bfhi(sv.y)};
        f32x4 shi = {bflo(sv.z), bfhi(sv.z), bflo(sv.w), bfhi(sv.w)};
        A += slo;
        B += shi;
        float di = sdv[idx];
        float v0 = di * A[0] + sbias[l8 + 0];
        float v1 = di * A[1] + sbias[l8 + 1];
        float v2 = di * A[2] + sbias[l8 + 2];
        float v3 = di * A[3] + sbias[l8 + 3];
        float v4 = di * B[0] + sbias[l8 + 4];
        float v5 = di * B[1] + sbias[l8 + 5];
        float v6 = di * B[2] + sbias[l8 + 6];
        float v7 = di * B[3] + sbias[l8 + 7];
        if (RELU) {
            v0 = fmaxf(v0, 0.f); v1 = fmaxf(v1, 0.f); v2 = fmaxf(v2, 0.f); v3 = fmaxf(v3, 0.f);
            v4 = fmaxf(v4, 0.f); v5 = fmaxf(v5, 0.f); v6 = fmaxf(v6, 0.f); v7 = fmaxf(v7, 0.f);
        }
        uint4 pk;
        pk.x = (unsigned)f2bf(v0) | ((unsigned)f2bf(v1) << 16);
        pk.y = (unsigned)f2bf(v2) | ((unsigned)f2bf(v3) << 16);
        pk.z = (unsigned)f2bf(v4) | ((unsigned)f2bf(v5) << 16);
        pk.w = (unsigned)f2bf(v6) | ((unsigned)f2bf(v7) << 16);
        *(uint4*)(out + (size_t)node * HID + l8) = pk;
    }
}

// ---------------- fused mean-pool + head (4 waves per graph; bounds precomputed) ----------------
__global__ __launch_bounds__(256) void k_poolout(const unsigned short* __restrict__ h2,
                                                 const int* __restrict__ bounds, int N,
                                                 const void* __restrict__ Wout,
                                                 const void* __restrict__ bout,
                                                 void* __restrict__ out,
                                                 const int* __restrict__ flags) {
    __shared__ float pr[HID];
    __shared__ float sacc[4][HID];
    int g = blockIdx.x;
    int start = min(max(bounds[g], 0), N);
    int endg = min(max(bounds[g + 1], start), N);
    int tid = threadIdx.x;
    int wv = tid >> 6, lane = tid & 63;
    int half = lane >> 5;
    int l = lane & 31;
    float s0 = 0.f, s1 = 0.f;
    for (int r = start + wv * 2 + half; r < endg; r += 8) {
        unsigned u = *(const unsigned*)(h2 + (size_t)r * HID + 2 * l);
        s0 += bflo(u);
        s1 += bfhi(u);
    }
    s0 += __shfl_xor(s0, 32);
    s1 += __shfl_xor(s1, 32);
    if (lane < 32) {
        sacc[wv][2 * l] = s0;
        sacc[wv][2 * l + 1] = s1;
    }
    __syncthreads();
    if (tid < HID) {
        float inv = 1.f / fmaxf((float)(endg - start), 1.f);
        pr[tid] = (sacc[0][tid] + sacc[1][tid] + sacc[2][tid] + sacc[3][tid]) * inv;
    }
    __syncthreads();
    int fp32 = flags[0];
    if (tid < NCLS) {
        float acc = ldf(bout, tid, fp32);
#pragma unroll 4
        for (int k = 0; k < HID; ++k)
            acc += pr[k] * ldf(Wout, k * NCLS + tid, fp32);
        if (fp32) ((float*)out)[g * NCLS + tid] = acc;
        else ((__hip_bfloat16*)out)[g * NCLS + tid] = __float2bfloat16(acc);
    }
}

extern "C" void kernel_launch(void* const* d_in, const int* in_sizes, int n_in,
                              void* d_out, int out_size, void* d_ws, size_t ws_size,
                              hipStream_t stream) {
    const void* x    = d_in[0];
    const void* ei   = d_in[1];
    const void* bat  = d_in[2];
    const void* W1   = d_in[3];
    const void* b1   = d_in[4];
    const void* W2   = d_in[5];
    const void* b2   = d_in[6];
    const void* Wout = d_in[7];
    const void* bout = d_in[8];

    const int N = in_sizes[0] / F_IN;
    const int E = in_sizes[1] / 2;
    const int G = out_size / NCLS;
    const int NB = (N + BW - 1) / BW;   // < NBMAX
    const int SZ = NB * BKCAP;          // padded csr/bkt length

    char* ws = (char*)d_ws;
    size_t off = 0;
    auto carve = [&](size_t bytes) -> void* {
        void* p = ws + off;
        off = (off + bytes + 255) & ~(size_t)255;
        return p;
    };
    int*            flags  = (int*)carve(64);
    int*            deg    = (int*)carve((size_t)N * 4);
    int*            cursor = (int*)carve((size_t)N * 4);
    float*          dinv   = (float*)carve((size_t)N * 4);
    int*            bcur   = (int*)carve((size_t)NB * 4);
    int*            bounds = (int*)carve((size_t)(G + 1) * 4);
    int*            csr    = (int*)carve((size_t)SZ * 4);
    int*            bkt    = (int*)carve((size_t)SZ * 4);
    unsigned short* t      = (unsigned short*)carve((size_t)N * HID * 2);  // t1, then t2
    unsigned short* h      = (unsigned short*)carve((size_t)N * HID * 2);  // h1, then h2
    (void)ws_size; (void)n_in;

    // sniff dtypes + init static bucket cursors
    k_detect<<<1, 512, 0, stream>>>(x, ei, flags, bcur, NB);
    // per-graph segment bounds (needs flags)
    k_bounds<<<(N + 255) / 256, 256, 0, stream>>>(bat, N, G, bounds, flags);

    // CSR build
    int na = (E + ACAP - 1) / ACAP;
    k_sortA<<<na, 512, 0, stream>>>(ei, E, NB, bcur, bkt, flags);
    k_sortB<<<NB, 512, 0, stream>>>(bkt, bcur, N, csr, cursor, deg, dinv);

    int gb = (N + 63) / 64;
    int ab = (N + 7) / 8;
    // layer 1
    k_gemm1<<<gb, 256, 0, stream>>>(x, W1, dinv, t, N, flags);
    k_agg<true><<<ab, 256, 0, stream>>>(t, csr, cursor, deg, dinv, b1, h, N, SZ, flags);
    // layer 2
    k_gemm2<<<gb, 256, 0, stream>>>(h, W2, dinv, t, N, flags);   // t now holds t2
    k_agg<false><<<ab, 256, 0, stream>>>(t, csr, cursor, deg, dinv, b2, h, N, SZ, flags);  // h holds h2
    // fused pool + head
    k_poolout<<<G, 256, 0, stream>>>(h, bounds, N, Wout, bout, d_out, flags);
}

// Round 5
// 204.638 us; speedup vs baseline: 1.1579x; 1.0139x over previous
//
#include <hip/hip_runtime.h>
#include <hip/hip_bf16.h>

#define F_IN 128
#define HID  64
#define NCLS 19
#define BW   128          // nodes per bucket (dst >> 7)
#define NBMAX 512         // max buckets (N <= 65536); also sortA scan width
#define ACAP 3072         // edges per k_sortA block (12 KB lbuf; 6 edges/thread in regs)
#define BKCAP 5120        // static per-bucket capacity (mean 4096, sigma 64 -> 16-sigma safe)
#define W1STR 136         // padded LDS stride (shorts) for W1^T rows
#define W2STR 72          // padded LDS stride (shorts) for W2^T rows
#define HROWSTR 72        // padded LDS stride (shorts) for h1 rows (breaks 128B-stride conflict)

typedef __bf16 bf16x8 __attribute__((ext_vector_type(8)));
typedef float  f32x4  __attribute__((ext_vector_type(4)));

// -------- adaptive loads: flags[0]=1 -> floats are fp32 (else bf16)
//          flags[1]=1 -> indices are int64 (else int32)
__device__ __forceinline__ float ldf(const void* p, long i, int fp32) {
    if (fp32) return ((const float*)p)[i];
    return __bfloat162float(((const __hip_bfloat16*)p)[i]);
}
__device__ __forceinline__ int ldi(const void* p, long i, int i64) {
    if (i64) return (int)((const long long*)p)[i];
    return ((const int*)p)[i];
}
__device__ __forceinline__ unsigned short f2bf(float f) {
    __hip_bfloat16 h = __float2bfloat16(f);   // RNE
    unsigned short r;
    __builtin_memcpy(&r, &h, 2);
    return r;
}
__device__ __forceinline__ float bflo(unsigned u) { return __uint_as_float(u << 16); }
__device__ __forceinline__ float bfhi(unsigned u) { return __uint_as_float(u & 0xffff0000u); }

__device__ __forceinline__ bf16x8 ldfrag(const unsigned short* p) {
    uint4 u = *(const uint4*)p;
    return __builtin_bit_cast(bf16x8, u);
}
// fp32 path vectorized: two float4 loads instead of 8 scalar dword loads
__device__ __forceinline__ bf16x8 ldfrag_any(const void* p, long off, int fp32) {
    if (!fp32) return ldfrag((const unsigned short*)p + off);
    const float4* f = (const float4*)((const float*)p + off);
    float4 u0 = f[0];
    float4 u1 = f[1];
    uint4 u = make_uint4((unsigned)f2bf(u0.x) | ((unsigned)f2bf(u0.y) << 16),
                         (unsigned)f2bf(u0.z) | ((unsigned)f2bf(u0.w) << 16),
                         (unsigned)f2bf(u1.x) | ((unsigned)f2bf(u1.y) << 16),
                         (unsigned)f2bf(u1.z) | ((unsigned)f2bf(u1.w) << 16));
    return __builtin_bit_cast(bf16x8, u);
}

// ---------------- dtype sniffer + static bucket-cursor init ----------------
__global__ __launch_bounds__(512) void k_detect(const void* x, const void* ei, int* flags,
                                                int* __restrict__ bcur, int NB) {
    int t = threadIdx.x;
    for (int b = t; b < NB; b += 512) bcur[b] = b * BKCAP;
    if (t != 0) return;
    const unsigned* xw = (const unsigned*)x;
    int bf16 = 1;
    for (int i = 0; i < 16; ++i) {
        unsigned w = xw[i];
        int elo = (w >> 7) & 0xFF;
        int ehi = (w >> 23) & 0xFF;
        if (elo < 100 || elo > 140 || ehi < 100 || ehi > 140) bf16 = 0;
    }
    const unsigned* iw = (const unsigned*)ei;
    int i64 = 1; unsigned anyev = 0;
    for (int k = 0; k < 8; ++k) {
        if (iw[2 * k + 1] != 0) i64 = 0;
        anyev |= iw[2 * k];
    }
    if (anyev == 0) i64 = 0;
    flags[0] = bf16 ? 0 : 1;
    flags[1] = i64;
}

// ---------------- per-graph segment bounds from sorted batch ----------------
__global__ __launch_bounds__(256) void k_bounds(const void* __restrict__ batch, int N, int G,
                                                int* __restrict__ bounds,
                                                const int* __restrict__ flags) {
    int i64 = flags[1];
    int i = blockIdx.x * 256 + threadIdx.x;
    if (i >= N) return;
    int b = min(max(ldi(batch, i, i64), 0), G - 1);
    int p = (i == 0) ? -1 : min(max(ldi(batch, (long)i - 1, i64), 0), G - 1);
    for (int g = p + 1; g <= b; ++g) bounds[g] = i;
    if (i == N - 1)
        for (int g = b + 1; g <= G; ++g) bounds[g] = N;
}

// ---------------- sort pass A: per-chunk LDS counting sort into static bucket regions ----------------
// dst values register-staged (6/thread): one global pass for histogram+scatter instead of two.
// Scan: wave-level shfl_up scans (barrier-free) + cross-wave combine.
__global__ __launch_bounds__(512) void k_sortA(const void* __restrict__ ei, int E, int nbuck,
                                               int* bcur, int* __restrict__ bkt,
                                               const int* __restrict__ flags) {
    __shared__ int lbuf[ACAP];
    __shared__ unsigned short lbkt[ACAP];   // slot -> bucket map (no binary search)
    __shared__ int lh[NBMAX];
    __shared__ int lsc[NBMAX];
    __shared__ int lcur[NBMAX];
    __shared__ int gbase[NBMAX];
    __shared__ int wpart[8];
    int i64 = flags[1];
    int t = threadIdx.x;                 // 0..511
    int e0 = blockIdx.x * ACAP;
    int e1 = min(E, e0 + ACAP);
    int cnt = e1 - e0;
    lh[t] = 0;
    __syncthreads();
    int dreg[6];                         // ACAP = 6*512 exactly
#pragma unroll
    for (int j = 0; j < 6; ++j) {
        int e = e0 + t + 512 * j;
        dreg[j] = (e < e1) ? ldi(ei, (long)E + e, i64) : -1;
    }
#pragma unroll
    for (int j = 0; j < 6; ++j)
        if (dreg[j] >= 0) atomicAdd(&lh[(dreg[j] >> 7) & (NBMAX - 1)], 1);
    __syncthreads();
    int v = lh[t];
    int lane = t & 63, wq = t >> 6;
    int incl = v;
#pragma unroll
    for (int off = 1; off < 64; off <<= 1) {
        int n = __shfl_up(incl, off);
        if (lane >= off) incl += n;
    }
    if (lane == 63) wpart[wq] = incl;
    __syncthreads();
    if (t == 0) {
        int acc = 0;
#pragma unroll
        for (int i = 0; i < 8; ++i) { int xx = wpart[i]; wpart[i] = acc; acc += xx; }
    }
    __syncthreads();
    int ex = wpart[wq] + incl - v;       // exclusive prefix
    lsc[t] = ex;
    lcur[t] = ex;
    gbase[t] = (v && t < nbuck) ? atomicAdd(&bcur[t], v) : 0;
    __syncthreads();
#pragma unroll
    for (int j = 0; j < 6; ++j) {
        if (dreg[j] < 0) continue;
        int e = e0 + t + 512 * j;
        int s = ldi(ei, e, i64);
        int b = (dreg[j] >> 7) & (NBMAX - 1);
        int r = atomicAdd(&lcur[b], 1);
        r = min(max(r, 0), ACAP - 1);
        lbuf[r] = (s << 7) | (dreg[j] & (BW - 1));
        lbkt[r] = (unsigned short)b;
    }
    __syncthreads();
    // coalesced writeout: slot i -> bucket via direct map
    for (int i = t; i < cnt; i += 512) {
        int lo = lbkt[i];
        int idx = gbase[lo] + (i - lsc[lo]);
        if (idx >= lo * BKCAP && idx < (lo + 1) * BKCAP) bkt[idx] = lbuf[i];
    }
}

// ---------------- sort pass B: per-bucket LDS counting sort -> csr, cursor, deg, dinv ----------------
__global__ __launch_bounds__(512) void k_sortB(const int* __restrict__ bkt,
                                               const int* __restrict__ bcur,
                                               int N,
                                               int* __restrict__ csr,
                                               int* __restrict__ cursor,
                                               int* __restrict__ deg,
                                               float* __restrict__ dinv) {
    __shared__ int lstage[BKCAP];       // 20 KB
    __shared__ int lcsr[BKCAP];         // 20 KB
    __shared__ int lh[BW], lsc[BW], lcur[BW];
    int b = blockIdx.x, t = threadIdx.x;
    int base = b * BKCAP;
    int cnt = min(max(bcur[b] - base, 0), BKCAP);
    if (t < BW) lh[t] = 0;
    __syncthreads();
    for (int i = t; i < cnt; i += 512) {
        int w = __builtin_nontemporal_load(&bkt[base + i]);
        lstage[i] = w;
        atomicAdd(&lh[w & (BW - 1)], 1);
    }
    __syncthreads();
    if (t < BW) lsc[t] = lh[t];
    __syncthreads();
    for (int off = 1; off < BW; off <<= 1) {
        int a = (t < BW && t >= off) ? lsc[t - off] : 0;
        __syncthreads();
        if (t < BW) lsc[t] += a;
        __syncthreads();
    }
    if (t < BW) {
        int ex = lsc[t] - lh[t];
        lcur[t] = ex;
        int n = b * BW + t;
        if (n < N) {
            cursor[n] = base + ex;
            deg[n] = lh[t];
            dinv[n] = rsqrtf((float)(lh[t] + 1));   // +1 self-loop
        }
    }
    __syncthreads();
    for (int i = t; i < cnt; i += 512) {
        int w = lstage[i];
        int r = atomicAdd(&lcur[w & (BW - 1)], 1);
        int sv = (int)((unsigned)w >> 7);
        if (sv >= N) sv = 0;                        // poison guard
        r = min(max(r, 0), BKCAP - 1);
        lcsr[r] = sv;
    }
    __syncthreads();
    for (int i = t; i < cnt; i += 512) csr[base + i] = lcsr[i];
}

// ---------------- GEMM1 (MFMA): t[i,:] = bf16(dinv[i] * (x[i,:] @ W1)) ----------------
__global__ __launch_bounds__(256) void k_gemm1(const void* __restrict__ x,
                                               const void* __restrict__ W,
                                               const float* __restrict__ dinv,
                                               unsigned short* __restrict__ t, int N,
                                               const int* __restrict__ flags) {
    __shared__ __align__(16) unsigned short wt[HID * W1STR];   // W1^T, padded
    int fp32 = flags[0];
    int tid = threadIdx.x;
    // coalesced staging: read W row-major (vectorized on fp32 path), write LDS transposed
    if (fp32) {
        const float* wf = (const float*)W;
        for (int i = tid * 4; i < F_IN * HID; i += 1024) {
            float4 w4 = *(const float4*)(wf + i);
            int k = i >> 6, n = i & 63;
            wt[(n + 0) * W1STR + k] = f2bf(w4.x);
            wt[(n + 1) * W1STR + k] = f2bf(w4.y);
            wt[(n + 2) * W1STR + k] = f2bf(w4.z);
            wt[(n + 3) * W1STR + k] = f2bf(w4.w);
        }
    } else {
        for (int i = tid; i < F_IN * HID; i += 256) {
            int k = i >> 6, n = i & 63;
            wt[n * W1STR + k] = f2bf(ldf(W, i, 0));
        }
    }
    __syncthreads();
    int wv = tid >> 6, lane = tid & 63;
    int quad = lane >> 4, l16 = lane & 15;
    int r0 = blockIdx.x * 64 + wv * 16;
    int rowA = min(r0 + l16, N - 1);
    bf16x8 a[4];
#pragma unroll
    for (int kq = 0; kq < 4; ++kq)
        a[kq] = ldfrag_any(x, (long)rowA * F_IN + kq * 32 + quad * 8, fp32);
    float di[4];
    int rowC = r0 + quad * 4;
#pragma unroll
    for (int r = 0; r < 4; ++r) di[r] = (rowC + r < N) ? dinv[rowC + r] : 0.f;
#pragma unroll
    for (int cg = 0; cg < 4; ++cg) {
        int col = cg * 16 + l16;
        f32x4 acc = {0.f, 0.f, 0.f, 0.f};
#pragma unroll
        for (int kq = 0; kq < 4; ++kq) {
            bf16x8 b = ldfrag(wt + col * W1STR + kq * 32 + quad * 8);
            acc = __builtin_amdgcn_mfma_f32_16x16x32_bf16(a[kq], b, acc, 0, 0, 0);
        }
#pragma unroll
        for (int r = 0; r < 4; ++r) {
            int row = rowC + r;
            if (row < N) t[(size_t)row * HID + col] = f2bf(di[r] * acc[r]);
        }
    }
}

// ---------------- FUSED layer-1 aggregation + GEMM2 ----------------
// Gather phase identical to k_agg<RELU=true>, but h1 rows stay in LDS (padded stride 72
// breaks the 128B-stride bank conflict). Epilogue: t2 = bf16(dinv * (h1 @ W2)) via the
// same 16x16x32 MFMA as the old k_gemm2 (rows 8..15 zero-padded; quad<2 stores).
// Kills the k_gemm2 dispatch + 12.8MB of h1 global traffic. Numerics identical
// (bf16-rounded h1, bf16 W2^T, f32 MFMA accum).
__global__ __launch_bounds__(256) void k_agg1mm(const unsigned short* __restrict__ t,
                                                const int* __restrict__ csr,
                                                const int* __restrict__ cursor,
                                                const int* __restrict__ deg,
                                                const float* __restrict__ dinv,
                                                const void* __restrict__ bias,   // b1
                                                const void* __restrict__ W2,
                                                unsigned short* __restrict__ out, // t2
                                                int N, int SZ, const int* __restrict__ flags) {
    __shared__ float sbias[HID];
    __shared__ int scur[8];
    __shared__ int sdeg[8];
    __shared__ float sdv[8];
    __shared__ __align__(16) unsigned short wt[HID * W2STR];    // W2^T, padded
    __shared__ __align__(16) unsigned short hrow[16][HROWSTR];  // h1 rows; 8 valid + 8 zero
    int fp32 = flags[0];
    int tid = threadIdx.x;
    int nb = blockIdx.x * 8;
    if (tid < HID) sbias[tid] = ldf(bias, tid, fp32);
    if (tid >= 64 && tid < 72) {
        int q = tid - 64;
        int node = nb + q;
        int c = 0, d = 0;
        float dv = 0.f;
        if (node < N) { c = cursor[node]; d = deg[node]; dv = dinv[node]; }
        scur[q] = c; sdeg[q] = d; sdv[q] = dv;
    }
    // zero pad rows 8..15 (full padded stride)
    for (int i = tid; i < 8 * HROWSTR; i += 256)
        hrow[8 + i / HROWSTR][i % HROWSTR] = 0;
    // stage W2^T
    if (fp32) {
        const float* wf = (const float*)W2;
        for (int i = tid * 4; i < HID * HID; i += 1024) {
            float4 w4 = *(const float4*)(wf + i);
            int k = i >> 6, n = i & 63;
            wt[(n + 0) * W2STR + k] = f2bf(w4.x);
            wt[(n + 1) * W2STR + k] = f2bf(w4.y);
            wt[(n + 2) * W2STR + k] = f2bf(w4.z);
            wt[(n + 3) * W2STR + k] = f2bf(w4.w);
        }
    } else {
        const unsigned short* ws16 = (const unsigned short*)W2;
        for (int i = tid; i < HID * HID; i += 256) {
            int k = i >> 6, n = i & 63;
            wt[n * W2STR + k] = ws16[i];
        }
    }
    __syncthreads();
    int wv = tid >> 6, lane = tid & 63;
    int half = lane >> 5;               // node within wave
    int idx = wv * 2 + half;            // node within block (0..7)
    int node = nb + idx;
    int l = lane & 31;
    int g = l >> 3;                     // neighbor slot 0..3
    int l8 = (l & 7) * 8;               // this lane's 8 features
    bool alive = (node < N);
    int snode = alive ? node : 0;
    int beg = scur[idx];
    int dg = sdeg[idx];
    beg = min(max(beg, 0), SZ);
    int end = beg + min(max(dg, 0), SZ - beg);
    // early self-loop fetch (overlaps with the gather loop)
    uint4 sv = make_uint4(0u, 0u, 0u, 0u);
    if (g == 0) sv = *(const uint4*)(t + (size_t)snode * HID + l8);
    f32x4 A = {0.f, 0.f, 0.f, 0.f};
    f32x4 B = {0.f, 0.f, 0.f, 0.f};
    int e = beg;
    for (; e + 32 <= end; e += 32) {    // full blocks: unconditional
        int s[8];
#pragma unroll
        for (int k = 0; k < 8; ++k) {
            int si = __builtin_nontemporal_load(&csr[e + 4 * k + g]);
            s[k] = ((unsigned)si < (unsigned)N) ? si : 0;
        }
        uint4 v[8];
#pragma unroll
        for (int k = 0; k < 8; ++k)
            v[k] = *(const uint4*)(t + (size_t)s[k] * HID + l8);
#pragma unroll
        for (int k = 0; k < 8; ++k) {
            f32x4 lo = {bflo(v[k].x), bfhi(v[k].x), bflo(v[k].y), bfhi(v[k].y)};
            f32x4 hi = {bflo(v[k].z), bfhi(v[k].z), bflo(v[k].w), bfhi(v[k].w)};
            A += lo;
            B += hi;
        }
    }
    if (e < end) {                      // tail: single masked block
        int s[8];
#pragma unroll
        for (int k = 0; k < 8; ++k) {
            int i = e + 4 * k + g;
            int si = __builtin_nontemporal_load(&csr[i < end ? i : end - 1]);
            s[k] = ((unsigned)si < (unsigned)N) ? si : 0;
        }
        uint4 v[8];
#pragma unroll
        for (int k = 0; k < 8; ++k)
            v[k] = *(const uint4*)(t + (size_t)s[k] * HID + l8);
#pragma unroll
        for (int k = 0; k < 8; ++k) {
            if (e + 4 * k + g < end) {
                f32x4 lo = {bflo(v[k].x), bfhi(v[k].x), bflo(v[k].y), bfhi(v[k].y)};
                f32x4 hi = {bflo(v[k].z), bfhi(v[k].z), bflo(v[k].w), bfhi(v[k].w)};
                A += lo;
                B += hi;
            }
        }
    }
#pragma unroll
    for (int m = 8; m <= 16; m <<= 1) {
#pragma unroll
        for (int c = 0; c < 4; ++c) {
            A[c] += __shfl_xor(A[c], m);
            B[c] += __shfl_xor(B[c], m);
        }
    }
    if (g == 0) {
        f32x4 slo = {bflo(sv.x), bfhi(sv.x), bflo(sv.y), bfhi(sv.y)};
        f32x4 shi = {bflo(sv.z), bfhi(sv.z), bflo(sv.w), bfhi(sv.w)};
        A += slo;
        B += shi;
        float di = sdv[idx];
        float v0 = fmaxf(di * A[0] + sbias[l8 + 0], 0.f);
        float v1 = fmaxf(di * A[1] + sbias[l8 + 1], 0.f);
        float v2 = fmaxf(di * A[2] + sbias[l8 + 2], 0.f);
        float v3 = fmaxf(di * A[3] + sbias[l8 + 3], 0.f);
        float v4 = fmaxf(di * B[0] + sbias[l8 + 4], 0.f);
        float v5 = fmaxf(di * B[1] + sbias[l8 + 5], 0.f);
        float v6 = fmaxf(di * B[2] + sbias[l8 + 6], 0.f);
        float v7 = fmaxf(di * B[3] + sbias[l8 + 7], 0.f);
        uint4 pk;
        pk.x = (unsigned)f2bf(v0) | ((unsigned)f2bf(v1) << 16);
        pk.y = (unsigned)f2bf(v2) | ((unsigned)f2bf(v3) << 16);
        pk.z = (unsigned)f2bf(v4) | ((unsigned)f2bf(v5) << 16);
        pk.w = (unsigned)f2bf(v6) | ((unsigned)f2bf(v7) << 16);
        *(uint4*)(&hrow[idx][l8]) = pk;   // LDS, not global
    }
    __syncthreads();
    // ---- fused GEMM2: wave wv computes cols wv*16..wv*16+15 for the block's 8 rows ----
    {
        int quad = lane >> 4, l16 = lane & 15;
        bf16x8 a2[2];
#pragma unroll
        for (int kq = 0; kq < 2; ++kq)
            a2[kq] = ldfrag(&hrow[l16][kq * 32 + quad * 8]);
        int col = wv * 16 + l16;
        f32x4 acc = {0.f, 0.f, 0.f, 0.f};
#pragma unroll
        for (int kq = 0; kq < 2; ++kq) {
            bf16x8 b = ldfrag(wt + col * W2STR + kq * 32 + quad * 8);
            acc = __builtin_amdgcn_mfma_f32_16x16x32_bf16(a2[kq], b, acc, 0, 0, 0);
        }
        if (quad < 2) {                 // rows 0..7 are the valid ones
#pragma unroll
            for (int r = 0; r < 4; ++r) {
                int row = quad * 4 + r;
                int n2 = nb + row;
                if (n2 < N) out[(size_t)n2 * HID + col] = f2bf(sdv[row] * acc[r]);
            }
        }
    }
}

// ---------------- layer-2 aggregation (gather t2, +b2, no relu) ----------------
template <bool RELU>
__global__ __launch_bounds__(256) void k_agg(const unsigned short* __restrict__ t,
                                             const int* __restrict__ csr,
                                             const int* __restrict__ cursor,
                                             const int* __restrict__ deg,
                                             const float* __restrict__ dinv,
                                             const void* __restrict__ bias,
                                             unsigned short* __restrict__ out,
                                             int N, int SZ, const int* __restrict__ flags) {
    __shared__ float sbias[HID];
    __shared__ int scur[8];
    __shared__ int sdeg[8];
    __shared__ float sdv[8];
    int tid = threadIdx.x;
    int nb = blockIdx.x * 8;
    if (tid < HID) sbias[tid] = ldf(bias, tid, flags[0]);
    if (tid >= 64 && tid < 72) {
        int q = tid - 64;
        int node = nb + q;
        int c = 0, d = 0;
        float dv = 0.f;
        if (node < N) { c = cursor[node]; d = deg[node]; dv = dinv[node]; }
        scur[q] = c; sdeg[q] = d; sdv[q] = dv;
    }
    __syncthreads();
    int wv = tid >> 6, lane = tid & 63;
    int half = lane >> 5;               // node within wave
    int idx = wv * 2 + half;            // node within block (0..7)
    int node = nb + idx;
    int l = lane & 31;
    int g = l >> 3;                     // neighbor slot 0..3
    int l8 = (l & 7) * 8;               // this lane's 8 features
    bool alive = (node < N);
    int snode = alive ? node : 0;
    int beg = scur[idx];
    int dg = sdeg[idx];
    beg = min(max(beg, 0), SZ);
    int end = beg + min(max(dg, 0), SZ - beg);
    uint4 sv = make_uint4(0u, 0u, 0u, 0u);
    if (g == 0) sv = *(const uint4*)(t + (size_t)snode * HID + l8);
    f32x4 A = {0.f, 0.f, 0.f, 0.f};
    f32x4 B = {0.f, 0.f, 0.f, 0.f};
    int e = beg;
    for (; e + 32 <= end; e += 32) {
        int s[8];
#pragma unroll
        for (int k = 0; k < 8; ++k) {
            int si = __builtin_nontemporal_load(&csr[e + 4 * k + g]);
            s[k] = ((unsigned)si < (unsigned)N) ? si : 0;
        }
        uint4 v[8];
#pragma unroll
        for (int k = 0; k < 8; ++k)
            v[k] = *(const uint4*)(t + (size_t)s[k] * HID + l8);
#pragma unroll
        for (int k = 0; k < 8; ++k) {
            f32x4 lo = {bflo(v[k].x), bfhi(v[k].x), bflo(v[k].y), bfhi(v[k].y)};
            f32x4 hi = {bflo(v[k].z), bfhi(v[k].z), bflo(v[k].w), bfhi(v[k].w)};
            A += lo;
            B += hi;
        }
    }
    if (e < end) {
        int s[8];
#pragma unroll
        for (int k = 0; k < 8; ++k) {
            int i = e + 4 * k + g;
            int si = __builtin_nontemporal_load(&csr[i < end ? i : end - 1]);
            s[k] = ((unsigned)si < (unsigned)N) ? si : 0;
        }
        uint4 v[8];
#pragma unroll
        for (int k = 0; k < 8; ++k)
            v[k] = *(const uint4*)(t + (size_t)s[k] * HID + l8);
#pragma unroll
        for (int k = 0; k < 8; ++k) {
            if (e + 4 * k + g < end) {
                f32x4 lo = {bflo(v[k].x), bfhi(v[k].x), bflo(v[k].y), bfhi(v[k].y)};
                f32x4 hi = {bflo(v[k].z), bfhi(v[k].z), bflo(v[k].w), bfhi(v[k].w)};
                A += lo;
                B += hi;
            }
        }
    }
#pragma unroll
    for (int m = 8; m <= 16; m <<= 1) {
#pragma unroll
        for (int c = 0; c < 4; ++c) {
            A[c] += __shfl_xor(A[c], m);
            B[c] += __shfl_xor(B[c], m);
        }
    }
    if (g == 0 && alive) {
        f32x4 slo = {bflo(sv.x), bfhi(sv.x), bflo(sv.y), bfhi(sv.y)};
        f32x4 shi = {bflo(sv.z), bfhi(sv.z), bflo(sv.w), bfhi(sv.w)};
        A += slo;
        B += shi;
        float di = sdv[idx];
        float v0 = di * A[0] + sbias[l8 + 0];
        float v1 = di * A[1] + sbias[l8 + 1];
        float v2 = di * A[2] + sbias[l8 + 2];
        float v3 = di * A[3] + sbias[l8 + 3];
        float v4 = di * B[0] + sbias[l8 + 4];
        float v5 = di * B[1] + sbias[l8 + 5];
        float v6 = di * B[2] + sbias[l8 + 6];
        float v7 = di * B[3] + sbias[l8 + 7];
        if (RELU) {
            v0 = fmaxf(v0, 0.f); v1 = fmaxf(v1, 0.f); v2 = fmaxf(v2, 0.f); v3 = fmaxf(v3, 0.f);
            v4 = fmaxf(v4, 0.f); v5 = fmaxf(v5, 0.f); v6 = fmaxf(v6, 0.f); v7 = fmaxf(v7, 0.f);
        }
        uint4 pk;
        pk.x = (unsigned)f2bf(v0) | ((unsigned)f2bf(v1) << 16);
        pk.y = (unsigned)f2bf(v2) | ((unsigned)f2bf(v3) << 16);
        pk.z = (unsigned)f2bf(v4) | ((unsigned)f2bf(v5) << 16);
        pk.w = (unsigned)f2bf(v6) | ((unsigned)f2bf(v7) << 16);
        *(uint4*)(out + (size_t)node * HID + l8) = pk;
    }
}

// ---------------- fused mean-pool + head (4 waves per graph; bounds precomputed) ----------------
__global__ __launch_bounds__(256) void k_poolout(const unsigned short* __restrict__ h2,
                                                 const int* __restrict__ bounds, int N,
                                                 const void* __restrict__ Wout,
                                                 const void* __restrict__ bout,
                                                 void* __restrict__ out,
                                                 const int* __restrict__ flags) {
    __shared__ float pr[HID];
    __shared__ float sacc[4][HID];
    int g = blockIdx.x;
    int start = min(max(bounds[g], 0), N);
    int endg = min(max(bounds[g + 1], start), N);
    int tid = threadIdx.x;
    int wv = tid >> 6, lane = tid & 63;
    int half = lane >> 5;
    int l = lane & 31;
    float s0 = 0.f, s1 = 0.f;
    for (int r = start + wv * 2 + half; r < endg; r += 8) {
        unsigned u = *(const unsigned*)(h2 + (size_t)r * HID + 2 * l);
        s0 += bflo(u);
        s1 += bfhi(u);
    }
    s0 += __shfl_xor(s0, 32);
    s1 += __shfl_xor(s1, 32);
    if (lane < 32) {
        sacc[wv][2 * l] = s0;
        sacc[wv][2 * l + 1] = s1;
    }
    __syncthreads();
    if (tid < HID) {
        float inv = 1.f / fmaxf((float)(endg - start), 1.f);
        pr[tid] = (sacc[0][tid] + sacc[1][tid] + sacc[2][tid] + sacc[3][tid]) * inv;
    }
    __syncthreads();
    int fp32 = flags[0];
    if (tid < NCLS) {
        float acc = ldf(bout, tid, fp32);
#pragma unroll 4
        for (int k = 0; k < HID; ++k)
            acc += pr[k] * ldf(Wout, k * NCLS + tid, fp32);
        if (fp32) ((float*)out)[g * NCLS + tid] = acc;
        else ((__hip_bfloat16*)out)[g * NCLS + tid] = __float2bfloat16(acc);
    }
}

extern "C" void kernel_launch(void* const* d_in, const int* in_sizes, int n_in,
                              void* d_out, int out_size, void* d_ws, size_t ws_size,
                              hipStream_t stream) {
    const void* x    = d_in[0];
    const void* ei   = d_in[1];
    const void* bat  = d_in[2];
    const void* W1   = d_in[3];
    const void* b1   = d_in[4];
    const void* W2   = d_in[5];
    const void* b2   = d_in[6];
    const void* Wout = d_in[7];
    const void* bout = d_in[8];

    const int N = in_sizes[0] / F_IN;
    const int E = in_sizes[1] / 2;
    const int G = out_size / NCLS;
    const int NB = (N + BW - 1) / BW;   // < NBMAX
    const int SZ = NB * BKCAP;          // padded csr/bkt length

    char* ws = (char*)d_ws;
    size_t off = 0;
    auto carve = [&](size_t bytes) -> void* {
        void* p = ws + off;
        off = (off + bytes + 255) & ~(size_t)255;
        return p;
    };
    int*            flags  = (int*)carve(64);
    int*            deg    = (int*)carve((size_t)N * 4);
    int*            cursor = (int*)carve((size_t)N * 4);
    float*          dinv   = (float*)carve((size_t)N * 4);
    int*            bcur   = (int*)carve((size_t)NB * 4);
    int*            bounds = (int*)carve((size_t)(G + 1) * 4);
    int*            csr    = (int*)carve((size_t)SZ * 4);
    int*            bkt    = (int*)carve((size_t)SZ * 4);
    unsigned short* t      = (unsigned short*)carve((size_t)N * HID * 2);  // t1, then h2
    unsigned short* h      = (unsigned short*)carve((size_t)N * HID * 2);  // t2
    (void)ws_size; (void)n_in;

    // sniff dtypes + init static bucket cursors
    k_detect<<<1, 512, 0, stream>>>(x, ei, flags, bcur, NB);
    // per-graph segment bounds (needs flags)
    k_bounds<<<(N + 255) / 256, 256, 0, stream>>>(bat, N, G, bounds, flags);

    // CSR build
    int na = (E + ACAP - 1) / ACAP;
    k_sortA<<<na, 512, 0, stream>>>(ei, E, NB, bcur, bkt, flags);
    k_sortB<<<NB, 512, 0, stream>>>(bkt, bcur, N, csr, cursor, deg, dinv);

    int gb = (N + 63) / 64;
    int ab = (N + 7) / 8;
    // layer 1: gemm1 -> t1; fused agg1+gemm2: gather t1, write t2 -> h
    k_gemm1<<<gb, 256, 0, stream>>>(x, W1, dinv, t, N, flags);
    k_agg1mm<<<ab, 256, 0, stream>>>(t, csr, cursor, deg, dinv, b1, W2, h, N, SZ, flags);
    // layer 2: gather t2 (h), write h2 -> t
    k_agg<false><<<ab, 256, 0, stream>>>(h, csr, cursor, deg, dinv, b2, t, N, SZ, flags);
    // fused pool + head
    k_poolout<<<G, 256, 0, stream>>>(t, bounds, N, Wout, bout, d_out, flags);
}